// Round 22
// baseline (261.627 us; speedup 1.0000x reference)
//
#include <hip/hip_runtime.h>

namespace {

typedef __attribute__((ext_vector_type(8))) short short8;   // MFMA A/B frag (8 bf16)
typedef __attribute__((ext_vector_type(4))) float floatx4;  // MFMA C/D frag

constexpr int T    = 512;
constexpr int H    = 64;
constexpr int TPB  = 512;   // 8 waves = 2/SIMD (R12/R16 topology: bracketed optimum)
constexpr int MB   = 8;     // grid 256 -> 1 block/CU, all CUs
constexpr int HST  = 128;   // ushorts per bat row, EXACT (rotation-swizzled, no pad)
constexpr int XSTR = 516;   // xs row stride (floats)
constexpr int FSTR = 68;    // hf32 row stride (floats, head only)

constexpr int DPP_ROR8 = 0x128;  // row_ror:8 -> lane i reads lane i^8 (within row of 16)

__device__ __forceinline__ ushort f2bf(float x) {  // fp32 -> bf16 RN-even (finite)
  unsigned u = __float_as_uint(x);
  unsigned r = u + 0x7fffu + ((u >> 16) & 1u);
  return (ushort)(r >> 16);
}
__device__ __forceinline__ float bf2f(ushort h) {
  return __uint_as_float(((unsigned)h) << 16);
}
__device__ __forceinline__ float fsig(float x) {
  return __builtin_amdgcn_rcpf(1.0f + __expf(-x));
}
__device__ __forceinline__ float ftanh(float x) {
  return fmaf(-2.0f, __builtin_amdgcn_rcpf(1.0f + __expf(2.0f * x)), 1.0f);
}
__device__ __forceinline__ float swz8(float v) {   // value from lane^8 (row of 16), VALU pipe
  return __int_as_float(__builtin_amdgcn_update_dpp(
      0, __float_as_int(v), DPP_ROR8, 0xf, 0xf, true));
}

// R22 = R20 resubmitted verbatim (R20/R21 benches failed: GPU acquisition
// timeouts — the kernel has never run; no measurement exists).
// R20 = R19 (215 us, verified) + chain cuts (R19 overshoot showed chain cycles
// are worth ~2x issue cycles — both waves/SIMD traverse the chain in phase):
//   (1) pinit folded into the MFMA C-operand. pinit[row,col] = bia[row] +
//       x[bat]*wih[row] is rank-1; tile d's C-init carries it on cols 0-7
//       (nhi=0 lanes), tile e's on cols 8-15 (nhi=1 lanes), zeros elsewhere —
//       the hi+lo col-sum then counts it exactly once per state. Masked
//       wih/bia are baked at setup; the per-step fmaf runs off-chain (before
//       the ds_read lands) and the merge loses its +pinit add.
//   (2) each tile's 4-deep MFMA chain -> 2x2-deep parallel chains (hi-chain
//       C=init, lo-chain C=0) + 1 add at merge: cuts ~2 dependent-MFMA
//       latencies off the chain for +8 v_add issue.
// Structure (verified): 8 waves x 2 tiles, gate-interleaved A-rows (R12),
// rot=24*bat swizzle (R18), own/send cndmask + 1 DPP merge (R9/R18),
// trunc hi/lo h-split + float2 x-read (R19), 1 barrier/step, h dbuf.
__global__ __launch_bounds__(TPB, 2)
void lstm_mfma(const float* __restrict__ xg,
               const float* __restrict__ W_ih,
               const float* __restrict__ W_hh,
               const float* __restrict__ b_ih,
               const float* __restrict__ b_hh,
               const float* __restrict__ fc1_w,
               const float* __restrict__ fc1_b,
               const float* __restrict__ fc2_w,
               const float* __restrict__ fc2_b,
               float* __restrict__ out)
{
  __shared__ __align__(16) ushort hA[MB * HST];   // h double-buffer (rot-swizzled rows)
  __shared__ __align__(16) ushort hB[MB * HST];
  __shared__ __align__(16) float  xs[MB * XSTR];
  __shared__ __align__(16) float  hf[MB * FSTR];  // final h fp32 (head; written once)
  __shared__ float zs[MB][16];

  const int tid  = threadIdx.x;
  const int b0   = blockIdx.x * MB;
  const int lane = tid & 63;
  const int wj   = tid >> 6;       // wave 0..7 -> tiles {2wj, 2wj+1}
  const int n    = lane & 15;      // MFMA col: batch n&7, type n>>3 (0=hi,1=lo)
  const int kg   = lane >> 4;      // k-group (A/B), row-quad (D)
  const int bat  = n & 7;
  const int nhi  = n >> 3;
  const int rot  = 24 * bat;       // per-bat rotation (ushorts; mult of 8 -> 16B-aligned)

  // ---- stage x (coalesced float4) ----
  for (int i = tid; i < MB * T / 4; i += TPB) {
    const int xb = i >> 7, tq = i & 127;
    float4 v = ((const float4*)(xg + (size_t)(b0 + xb) * T))[tq];
    *(float4*)&xs[xb * XSTR + tq * 4] = v;
  }
  // ---- zero h buffers (h0 = 0) ----
  for (int i = tid; i < MB * HST; i += TPB) { hA[i] = 0; hB[i] = 0; }

  // ---- A-frags for tiles 2wj, 2wj+1 (gate-interleaved permutation, verified R12) ----
  short8 whi[2][2], wlo[2][2];     // [tile][k-half]
#pragma unroll
  for (int tt = 0; tt < 2; ++tt) {
    const int r    = 2 * wj + tt;
    const int arow = 64 * (n & 3) + 4 * r + (n >> 2);   // gate n&3, local unit n>>2
    const float* wr = W_hh + arow * H + 8 * kg;
    const float4 p0 = *(const float4*)(wr + 0);
    const float4 p1 = *(const float4*)(wr + 4);
    const float4 p2 = *(const float4*)(wr + 32);
    const float4 p3 = *(const float4*)(wr + 36);
    const float v0[8] = {p0.x, p0.y, p0.z, p0.w, p1.x, p1.y, p1.z, p1.w};
    const float v1[8] = {p2.x, p2.y, p2.z, p2.w, p3.x, p3.y, p3.z, p3.w};
#pragma unroll
    for (int j = 0; j < 8; ++j) {
      const ushort h0 = f2bf(v0[j]);
      whi[tt][0][j] = (short)h0;
      wlo[tt][0][j] = (short)f2bf(v0[j] - bf2f(h0));   // exact remainder, then RN
      const ushort h1 = f2bf(v1[j]);
      whi[tt][1][j] = (short)h1;
      wlo[tt][1][j] = (short)f2bf(v1[j] - bf2f(h1));
    }
  }

  // ---- owned c-state: unit u = 8wj + 4nhi + kg, batch bat ----
  // Masked init weights: my owned unit's rows sit in MY tile (d for nhi=0,
  // e for nhi=1) at MY col — bake the tile masking into the registers.
  const int u = 8 * wj + 4 * nhi + kg;
  float biad[4], wihd[4], biae[4], wihe[4];
#pragma unroll
  for (int j = 0; j < 4; ++j) {                 // gate rows: i,f,g,o = 64j + u
    const int row = 64 * j + u;
    const float bj = b_ih[row] + b_hh[row];
    const float wj_ = W_ih[row];
    biad[j] = nhi ? 0.0f : bj;   wihd[j] = nhi ? 0.0f : wj_;
    biae[j] = nhi ? bj : 0.0f;   wihe[j] = nhi ? wj_ : 0.0f;
  }

  // ---- swizzled LDS offsets (precomputed; rotation wrap => separate mods) ----
  const int Lrd   = 64 * nhi + 8 * kg;                      // logical read base
  const int rd0   = bat * HST + ((Lrd      + rot) & 127);   // f0 (k 0..31 of my type)
  const int rd1   = bat * HST + ((Lrd + 32 + rot) & 127);   // f1 (k 32..63)
  const int whi_o = bat * HST + ((u        + rot) & 127);   // h hi write
  const int wlo_o = bat * HST + ((u + 64   + rot) & 127);   // h lo write
  const float* xq = &xs[bat * XSTR];
  float c = 0.0f, hk = 0.0f;

  __syncthreads();

#define STEP(HR, HW, XT)                                                       \
  {                                                                            \
    /* off-chain: rank-1 C-init from registers (hidden under ds_read) */       \
    floatx4 id, ie;                                                            \
    _Pragma("unroll") for (int j = 0; j < 4; ++j) {                            \
      id[j] = fmaf((XT), wihd[j], biad[j]);                                    \
      ie[j] = fmaf((XT), wihe[j], biae[j]);                                    \
    }                                                                          \
    const short8 f0 = *(const short8*)((HR) + rd0);                            \
    const short8 f1 = *(const short8*)((HR) + rd1);                            \
    const floatx4 zf = {0.f, 0.f, 0.f, 0.f};                                   \
    /* 2x2-deep parallel chains per tile (chain cut; +1 add at merge) */       \
    floatx4 dA = __builtin_amdgcn_mfma_f32_16x16x32_bf16(whi[0][0], f0, id, 0, 0, 0); \
    floatx4 dB = __builtin_amdgcn_mfma_f32_16x16x32_bf16(wlo[0][0], f0, zf, 0, 0, 0); \
    floatx4 eA = __builtin_amdgcn_mfma_f32_16x16x32_bf16(whi[1][0], f0, ie, 0, 0, 0); \
    floatx4 eB = __builtin_amdgcn_mfma_f32_16x16x32_bf16(wlo[1][0], f0, zf, 0, 0, 0); \
    dA = __builtin_amdgcn_mfma_f32_16x16x32_bf16(whi[0][1], f1, dA, 0, 0, 0);  \
    dB = __builtin_amdgcn_mfma_f32_16x16x32_bf16(wlo[0][1], f1, dB, 0, 0, 0);  \
    eA = __builtin_amdgcn_mfma_f32_16x16x32_bf16(whi[1][1], f1, eA, 0, 0, 0);  \
    eB = __builtin_amdgcn_mfma_f32_16x16x32_bf16(wlo[1][1], f1, eB, 0, 0, 0);  \
    float p[4];                                                                \
    _Pragma("unroll") for (int j = 0; j < 4; ++j) {                            \
      const float sd = dA[j] + dB[j];                                          \
      const float se = eA[j] + eB[j];                                          \
      const float own  = nhi ? se : sd;   /* my tile @ my col type   */        \
      const float send = nhi ? sd : se;   /* partner's tile @ my col */        \
      p[j] = own + swz8(send);            /* pinit already inside */           \
    }                                                                          \
    const float ig = fsig(p[0]);                                               \
    const float fg = fsig(p[1]);                                               \
    const float gc = ftanh(p[2]);                                              \
    const float og = fsig(p[3]);                                               \
    c  = fmaf(fg, c, ig * gc);                                                 \
    hk = og * ftanh(c);                                                        \
    /* trunc split both halves (R19): hi = trunc(hk), lo = trunc(hk-hi) */     \
    const ushort hib = (ushort)(__float_as_uint(hk) >> 16);                    \
    const float  rem = hk - bf2f(hib);                                         \
    (HW)[whi_o] = hib;                                                         \
    (HW)[wlo_o] = (ushort)(__float_as_uint(rem) >> 16);                        \
    __syncthreads();                                                           \
  }

  for (int t = 0; t < T; t += 2) {
    const float2 x2 = *(const float2*)(xq + t);   // one b64 read feeds both steps
    STEP(hA, hB, x2.x);
    STEP(hB, hA, x2.y);
  }
#undef STEP

  // ---- final h (fp32, from registers) -> LDS once; then the head ----
  hf[bat * FSTR + u] = hk;
  __syncthreads();
  if (tid < MB * 16) {
    const int bq = tid >> 4, j2 = tid & 15;   // 8 batches x 16 hidden2
    float s = fc1_b[j2];
    const float* fw = fc1_w + j2 * H;
#pragma unroll
    for (int k = 0; k < H; ++k) s = fmaf(hf[bq * FSTR + k], fw[k], s);
    s = fmaxf(s, 0.0f);
    zs[bq][j2] = s * fc2_w[j2];
  }
  __syncthreads();
  if (tid < MB) {
    float s = fc2_b[0];
#pragma unroll
    for (int j = 0; j < 16; ++j) s += zs[tid][j];
    out[b0 + tid] = s;
  }
}

}  // namespace

extern "C" void kernel_launch(void* const* d_in, const int* in_sizes, int n_in,
                              void* d_out, int out_size, void* d_ws, size_t ws_size,
                              hipStream_t stream) {
  const float* xg    = (const float*)d_in[0];
  const float* W_ih  = (const float*)d_in[1];
  const float* W_hh  = (const float*)d_in[2];
  const float* b_ih  = (const float*)d_in[3];
  const float* b_hh  = (const float*)d_in[4];
  const float* fc1_w = (const float*)d_in[5];
  const float* fc1_b = (const float*)d_in[6];
  const float* fc2_w = (const float*)d_in[7];
  const float* fc2_b = (const float*)d_in[8];
  float* out = (float*)d_out;

  dim3 grid(2048 / MB);   // 256 blocks -> 1 per CU, 8 waves = 2/SIMD
  dim3 block(TPB);
  hipLaunchKernelGGL(lstm_mfma, grid, block, 0, stream,
                     xg, W_ih, W_hh, b_ih, b_hh, fc1_w, fc1_b, fc2_w, fc2_b, out);
}

// Round 23
// 250.522 us; speedup vs baseline: 1.0443x; 1.0443x over previous
//
#include <hip/hip_runtime.h>

namespace {

typedef __attribute__((ext_vector_type(8))) short short8;   // MFMA A/B frag (8 bf16)
typedef __attribute__((ext_vector_type(4))) float floatx4;  // MFMA C/D frag

constexpr int T    = 512;
constexpr int H    = 64;
constexpr int TPB  = 512;   // 8 waves = 2/SIMD (R12/R16 topology: bracketed optimum)
constexpr int MB   = 8;     // grid 256 -> 1 block/CU, all CUs
constexpr int HST  = 128;   // ushorts per bat row, EXACT (rotation-swizzled, no pad)
constexpr int XSTR = 516;   // xs row stride (floats)
constexpr int FSTR = 68;    // hf32 row stride (floats, head only)

constexpr int DPP_ROR8 = 0x128;  // row_ror:8 -> lane i reads lane i^8 (within row of 16)

__device__ __forceinline__ ushort f2bf(float x) {  // fp32 -> bf16 RN-even (finite)
  unsigned u = __float_as_uint(x);
  unsigned r = u + 0x7fffu + ((u >> 16) & 1u);
  return (ushort)(r >> 16);
}
__device__ __forceinline__ float bf2f(ushort h) {
  return __uint_as_float(((unsigned)h) << 16);
}
__device__ __forceinline__ float fsig(float x) {
  return __builtin_amdgcn_rcpf(1.0f + __expf(-x));
}
__device__ __forceinline__ float ftanh(float x) {
  return fmaf(-2.0f, __builtin_amdgcn_rcpf(1.0f + __expf(2.0f * x)), 1.0f);
}
__device__ __forceinline__ float swz8(float v) {   // value from lane^8 (row of 16), VALU pipe
  return __int_as_float(__builtin_amdgcn_update_dpp(
      0, __float_as_int(v), DPP_ROR8, 0xf, 0xf, true));
}

// R23 = R19 restored verbatim (best verified: 215 us profiled, absmax 3e-5).
// R22 refuted the R20 chain cuts (228 us): R19's d/e tiles were ALREADY two
// independent 4-deep MFMA chains — the scheduler interleaves them, so splitting
// into 2x2-deep only added issue (+16 ops) and a fmaf->MFMA dependency.
// Evidence base (closed):
//   - Topology: R6/R10/R11/R13/R15 bracket the space; 8 waves x dup-free
//     2-tiles, 2 waves/SIMD, one barrier/step is the optimum. All-to-all h
//     dependence forces a full barrier + LDS round-trip per step.
//   - Issue diet: R16 fused chains, R18 merge diet, R19 trunc-split + x-pair.
//   - LDS conflicts: R17/R18 swizzle; residual 8.4M = irreducible dword pairs.
// Step ~1010 cyc = ~600 issue/SIMD + ~330 in-phase chain stall: a latency
// floor of the sequential recurrence (512 dependent steps), not a pipe limit.
__global__ __launch_bounds__(TPB, 2)
void lstm_mfma(const float* __restrict__ xg,
               const float* __restrict__ W_ih,
               const float* __restrict__ W_hh,
               const float* __restrict__ b_ih,
               const float* __restrict__ b_hh,
               const float* __restrict__ fc1_w,
               const float* __restrict__ fc1_b,
               const float* __restrict__ fc2_w,
               const float* __restrict__ fc2_b,
               float* __restrict__ out)
{
  __shared__ __align__(16) ushort hA[MB * HST];   // h double-buffer (rot-swizzled rows)
  __shared__ __align__(16) ushort hB[MB * HST];
  __shared__ __align__(16) float  xs[MB * XSTR];
  __shared__ __align__(16) float  hf[MB * FSTR];  // final h fp32 (head; written once)
  __shared__ float zs[MB][16];

  const int tid  = threadIdx.x;
  const int b0   = blockIdx.x * MB;
  const int lane = tid & 63;
  const int wj   = tid >> 6;       // wave 0..7 -> tiles {2wj, 2wj+1}
  const int n    = lane & 15;      // MFMA col: batch n&7, type n>>3 (0=hi,1=lo)
  const int kg   = lane >> 4;      // k-group (A/B), row-quad (D)
  const int bat  = n & 7;
  const int nhi  = n >> 3;
  const int rot  = 24 * bat;       // per-bat rotation (ushorts; mult of 8 -> 16B-aligned)

  // ---- stage x (coalesced float4) ----
  for (int i = tid; i < MB * T / 4; i += TPB) {
    const int xb = i >> 7, tq = i & 127;
    float4 v = ((const float4*)(xg + (size_t)(b0 + xb) * T))[tq];
    *(float4*)&xs[xb * XSTR + tq * 4] = v;
  }
  // ---- zero h buffers (h0 = 0) ----
  for (int i = tid; i < MB * HST; i += TPB) { hA[i] = 0; hB[i] = 0; }

  // ---- A-frags for tiles 2wj, 2wj+1 (gate-interleaved permutation, verified R12) ----
  short8 whi[2][2], wlo[2][2];     // [tile][k-half]
#pragma unroll
  for (int tt = 0; tt < 2; ++tt) {
    const int r    = 2 * wj + tt;
    const int arow = 64 * (n & 3) + 4 * r + (n >> 2);   // gate n&3, local unit n>>2
    const float* wr = W_hh + arow * H + 8 * kg;
    const float4 p0 = *(const float4*)(wr + 0);
    const float4 p1 = *(const float4*)(wr + 4);
    const float4 p2 = *(const float4*)(wr + 32);
    const float4 p3 = *(const float4*)(wr + 36);
    const float v0[8] = {p0.x, p0.y, p0.z, p0.w, p1.x, p1.y, p1.z, p1.w};
    const float v1[8] = {p2.x, p2.y, p2.z, p2.w, p3.x, p3.y, p3.z, p3.w};
#pragma unroll
    for (int j = 0; j < 8; ++j) {
      const ushort h0 = f2bf(v0[j]);
      whi[tt][0][j] = (short)h0;
      wlo[tt][0][j] = (short)f2bf(v0[j] - bf2f(h0));   // exact remainder, then RN
      const ushort h1 = f2bf(v1[j]);
      whi[tt][1][j] = (short)h1;
      wlo[tt][1][j] = (short)f2bf(v1[j] - bf2f(h1));
    }
  }

  // ---- owned c-state: unit u = 8wj + 4nhi + kg, batch bat ----
  const int u = 8 * wj + 4 * nhi + kg;
  float bia[4], wih[4];
#pragma unroll
  for (int j = 0; j < 4; ++j) {                 // gate rows: i,f,g,o = 64j + u
    const int row = 64 * j + u;
    bia[j] = b_ih[row] + b_hh[row];
    wih[j] = W_ih[row];
  }

  // ---- swizzled LDS offsets (precomputed; rotation wrap => separate mods) ----
  const int Lrd   = 64 * nhi + 8 * kg;                      // logical read base
  const int rd0   = bat * HST + ((Lrd      + rot) & 127);   // f0 (k 0..31 of my type)
  const int rd1   = bat * HST + ((Lrd + 32 + rot) & 127);   // f1 (k 32..63)
  const int whi_o = bat * HST + ((u        + rot) & 127);   // h hi write
  const int wlo_o = bat * HST + ((u + 64   + rot) & 127);   // h lo write
  const float* xq = &xs[bat * XSTR];
  float c = 0.0f, hk = 0.0f;

  __syncthreads();

#define STEP(HR, HW, XT)                                                       \
  {                                                                            \
    const short8 f0 = *(const short8*)((HR) + rd0);                            \
    const short8 f1 = *(const short8*)((HR) + rd1);                            \
    const floatx4 zf = {0.f, 0.f, 0.f, 0.f};                                   \
    /* one fused 4-deep chain per tile (all 4 split terms C-accumulated); */   \
    /* d and e are independent chains — HW interleaves them (R22 lesson) */    \
    floatx4 d = __builtin_amdgcn_mfma_f32_16x16x32_bf16(whi[0][0], f0, zf, 0, 0, 0); \
    floatx4 e = __builtin_amdgcn_mfma_f32_16x16x32_bf16(whi[1][0], f0, zf, 0, 0, 0); \
    d = __builtin_amdgcn_mfma_f32_16x16x32_bf16(wlo[0][0], f0, d, 0, 0, 0);    \
    e = __builtin_amdgcn_mfma_f32_16x16x32_bf16(wlo[1][0], f0, e, 0, 0, 0);    \
    d = __builtin_amdgcn_mfma_f32_16x16x32_bf16(whi[0][1], f1, d, 0, 0, 0);    \
    e = __builtin_amdgcn_mfma_f32_16x16x32_bf16(whi[1][1], f1, e, 0, 0, 0);    \
    d = __builtin_amdgcn_mfma_f32_16x16x32_bf16(wlo[0][1], f1, d, 0, 0, 0);    \
    e = __builtin_amdgcn_mfma_f32_16x16x32_bf16(wlo[1][1], f1, e, 0, 0, 0);    \
    float p[4];                                                                \
    _Pragma("unroll") for (int j = 0; j < 4; ++j) {                            \
      const float own  = nhi ? e[j] : d[j];   /* my tile @ my col type   */    \
      const float send = nhi ? d[j] : e[j];   /* partner's tile @ my col */    \
      p[j] = own + swz8(send) + fmaf((XT), wih[j], bia[j]);                    \
    }                                                                          \
    const float ig = fsig(p[0]);                                               \
    const float fg = fsig(p[1]);                                               \
    const float gc = ftanh(p[2]);                                              \
    const float og = fsig(p[3]);                                               \
    c  = fmaf(fg, c, ig * gc);                                                 \
    hk = og * ftanh(c);                                                        \
    /* trunc split both halves (R19): hi = trunc(hk), lo = trunc(hk-hi) */     \
    const ushort hib = (ushort)(__float_as_uint(hk) >> 16);                    \
    const float  rem = hk - bf2f(hib);                                         \
    (HW)[whi_o] = hib;                                                         \
    (HW)[wlo_o] = (ushort)(__float_as_uint(rem) >> 16);                        \
    __syncthreads();                                                           \
  }

  for (int t = 0; t < T; t += 2) {
    const float2 x2 = *(const float2*)(xq + t);   // one b64 read feeds both steps
    STEP(hA, hB, x2.x);
    STEP(hB, hA, x2.y);
  }
#undef STEP

  // ---- final h (fp32, from registers) -> LDS once; then the head ----
  hf[bat * FSTR + u] = hk;
  __syncthreads();
  if (tid < MB * 16) {
    const int bq = tid >> 4, j2 = tid & 15;   // 8 batches x 16 hidden2
    float s = fc1_b[j2];
    const float* fw = fc1_w + j2 * H;
#pragma unroll
    for (int k = 0; k < H; ++k) s = fmaf(hf[bq * FSTR + k], fw[k], s);
    s = fmaxf(s, 0.0f);
    zs[bq][j2] = s * fc2_w[j2];
  }
  __syncthreads();
  if (tid < MB) {
    float s = fc2_b[0];
#pragma unroll
    for (int j = 0; j < 16; ++j) s += zs[tid][j];
    out[b0 + tid] = s;
  }
}

}  // namespace

extern "C" void kernel_launch(void* const* d_in, const int* in_sizes, int n_in,
                              void* d_out, int out_size, void* d_ws, size_t ws_size,
                              hipStream_t stream) {
  const float* xg    = (const float*)d_in[0];
  const float* W_ih  = (const float*)d_in[1];
  const float* W_hh  = (const float*)d_in[2];
  const float* b_ih  = (const float*)d_in[3];
  const float* b_hh  = (const float*)d_in[4];
  const float* fc1_w = (const float*)d_in[5];
  const float* fc1_b = (const float*)d_in[6];
  const float* fc2_w = (const float*)d_in[7];
  const float* fc2_b = (const float*)d_in[8];
  float* out = (float*)d_out;

  dim3 grid(2048 / MB);   // 256 blocks -> 1 per CU, 8 waves = 2/SIMD
  dim3 block(TPB);
  hipLaunchKernelGGL(lstm_mfma, grid, block, 0, stream,
                     xg, W_ih, W_hh, b_ih, b_hh, fc1_w, fc1_b, fc2_w, fc2_b, out);
}